// Round 4
// baseline (267.434 us; speedup 1.0000x reference)
//
#include <hip/hip_runtime.h>
#include <math.h>

#define N_NODES 50000
#define N_EDGES 1600000
#define IN_DIM 128
#define N_HEADS 8
#define OUT_DIM 16
#define HD 128            // N_HEADS * OUT_DIM
#define DEG_CAP 128       // LDS-cached edges per node in aggregate
#define NBUCK 196         // ceil(N_NODES / 256) coarse buckets (256 nodes each)
#define BCAP 12288        // region capacity per bucket (avg ~8163)
#define CHUNK 2048        // edges per k_bin block
#define BIN_BLOCKS ((N_EDGES + CHUNK - 1) / CHUNK)   // 782

__device__ __forceinline__ unsigned short f2bf(float f) {
    union { float f; unsigned int u; } v; v.f = f;
    unsigned int u = v.u;
    unsigned int r = (u + 0x7fffu + ((u >> 16) & 1u)) >> 16;   // RN-even
    return (unsigned short)r;
}

// ---------------- W transpose + zero bin state (one-time, fused) ----------------
__global__ void k_transpose_w(const float* __restrict__ W, float* __restrict__ Wt,
                              int* __restrict__ bucket_cnt, int* __restrict__ ovf_cnt) {
    if (blockIdx.x == 0) {
        int t = threadIdx.x;
        if (t < NBUCK) bucket_cnt[t] = 0;
        if (t == 0) *ovf_cnt = 0;
    }
    int flat4 = blockIdx.x * blockDim.x + threadIdx.x;
    if (flat4 >= (HD * IN_DIM) / 4) return;
    int c  = flat4 >> 5;
    int k4 = flat4 & 31;
    float4 v = ((const float4*)W)[flat4];
    int k = k4 * 4;
    Wt[(k + 0) * HD + c] = v.x;
    Wt[(k + 1) * HD + c] = v.y;
    Wt[(k + 2) * HD + c] = v.z;
    Wt[(k + 3) * HD + c] = v.w;
}

// ---------------- projection: ft(bf16) = x @ W^T, a1/a2 head dots ----------------
__global__ __launch_bounds__(256) void k_project(
    const float* __restrict__ x, const float* __restrict__ Wt,
    const float* __restrict__ attn_l, const float* __restrict__ attn_r,
    unsigned short* __restrict__ ftb, float* __restrict__ a1, float* __restrict__ a2) {
    __shared__ float red_l[32][32];
    __shared__ float red_r[32][32];

    int tid = threadIdx.x;
    int cb = (tid & 31) * 4;
    int nb = (tid >> 5) * 4;
    int node0 = blockIdx.x * 32;

    float4 acc[4];
    acc[0] = acc[1] = acc[2] = acc[3] = make_float4(0.f, 0.f, 0.f, 0.f);

    const float* xrow[4];
#pragma unroll
    for (int i = 0; i < 4; i++) {
        int n = node0 + nb + i;
        if (n >= N_NODES) n = N_NODES - 1;
        xrow[i] = x + (size_t)n * IN_DIM;
    }

    for (int k = 0; k < IN_DIM; k += 4) {
        float4 w0 = *(const float4*)(Wt + (k + 0) * HD + cb);
        float4 w1 = *(const float4*)(Wt + (k + 1) * HD + cb);
        float4 w2 = *(const float4*)(Wt + (k + 2) * HD + cb);
        float4 w3 = *(const float4*)(Wt + (k + 3) * HD + cb);
#pragma unroll
        for (int i = 0; i < 4; i++) {
            float4 xv = *(const float4*)(xrow[i] + k);
            acc[i].x = fmaf(xv.w, w3.x, fmaf(xv.z, w2.x, fmaf(xv.y, w1.x, fmaf(xv.x, w0.x, acc[i].x))));
            acc[i].y = fmaf(xv.w, w3.y, fmaf(xv.z, w2.y, fmaf(xv.y, w1.y, fmaf(xv.x, w0.y, acc[i].y))));
            acc[i].z = fmaf(xv.w, w3.z, fmaf(xv.z, w2.z, fmaf(xv.y, w1.z, fmaf(xv.x, w0.z, acc[i].z))));
            acc[i].w = fmaf(xv.w, w3.w, fmaf(xv.z, w2.w, fmaf(xv.y, w1.w, fmaf(xv.x, w0.w, acc[i].w))));
        }
    }

#pragma unroll
    for (int i = 0; i < 4; i++) {
        int n = node0 + nb + i;
        if (n < N_NODES) {
            ushort4 us;
            us.x = f2bf(acc[i].x); us.y = f2bf(acc[i].y);
            us.z = f2bf(acc[i].z); us.w = f2bf(acc[i].w);
            *(ushort4*)(ftb + (size_t)n * HD + cb) = us;
        }
    }

    int h   = cb >> 4;
    int sub = cb & 15;
    float4 al = *(const float4*)(attn_l + h * OUT_DIM + sub);
    float4 ar = *(const float4*)(attn_r + h * OUT_DIM + sub);
    int col = (h << 2) | (sub >> 2);
#pragma unroll
    for (int i = 0; i < 4; i++) {
        float pl = acc[i].x * al.x + acc[i].y * al.y + acc[i].z * al.z + acc[i].w * al.w;
        float pr = acc[i].x * ar.x + acc[i].y * ar.y + acc[i].z * ar.z + acc[i].w * ar.w;
        red_l[nb + i][col] = pl;
        red_r[nb + i][col] = pr;
    }
    __syncthreads();
    int nl = tid >> 3, hh = tid & 7;
    int n = node0 + nl;
    if (n < N_NODES) {
        float s1 = red_l[nl][hh * 4 + 0] + red_l[nl][hh * 4 + 1] + red_l[nl][hh * 4 + 2] + red_l[nl][hh * 4 + 3];
        float s2 = red_r[nl][hh * 4 + 0] + red_r[nl][hh * 4 + 1] + red_r[nl][hh * 4 + 2] + red_r[nl][hh * 4 + 3];
        a1[n * N_HEADS + hh] = s1;
        a2[n * N_HEADS + hh] = s2;
    }
}

// ---------------- pass 1: bin edges into coarse buckets (contiguous runs) --------
__global__ __launch_bounds__(256) void k_bin(
    const int* __restrict__ src, const int* __restrict__ dst,
    unsigned int* __restrict__ region, int* __restrict__ bucket_cnt,
    int* __restrict__ ovf_cnt, unsigned int* __restrict__ ovf) {
    __shared__ unsigned int stage[CHUNK];        // 8 KB
    __shared__ int hist[256], scan[256], loff[256], lcur[256], rbase[256];
    int t = threadIdx.x;
    int base = blockIdx.x * CHUNK;
    int nvalid = min(CHUNK, N_EDGES - base);

    hist[t] = 0;
    __syncthreads();

    unsigned int mypack[CHUNK / 256];
#pragma unroll
    for (int k = 0; k < CHUNK / 256; k++) {
        int i = t + k * 256;
        if (i < nvalid) {
            int s = src[base + i];
            int d = dst[base + i];
            unsigned int p = ((unsigned int)d << 16) | (unsigned int)s;
            mypack[k] = p;
            atomicAdd(&hist[d >> 8], 1);
        }
    }
    __syncthreads();
    int h = hist[t];
    scan[t] = h;
    __syncthreads();
    for (int d2 = 1; d2 < 256; d2 <<= 1) {
        int u = (t >= d2) ? scan[t - d2] : 0;
        __syncthreads();
        scan[t] += u;
        __syncthreads();
    }
    int excl = scan[t] - h;
    loff[t] = excl;
    lcur[t] = excl;
    rbase[t] = (t < NBUCK && h > 0) ? atomicAdd(&bucket_cnt[t], h) : 0;
    __syncthreads();
#pragma unroll
    for (int k = 0; k < CHUNK / 256; k++) {
        int i = t + k * 256;
        if (i < nvalid) {
            unsigned int p = mypack[k];
            int slot = atomicAdd(&lcur[p >> 24], 1);
            stage[slot] = p;
        }
    }
    __syncthreads();
    for (int i = t; i < nvalid; i += 256) {
        unsigned int p = stage[i];
        int b = p >> 24;
        int pos = rbase[b] + (i - loff[b]);
        if (pos < BCAP) region[(size_t)b * BCAP + pos] = p;
        else { int o = atomicAdd(ovf_cnt, 1); ovf[o] = p; }
    }
}

// ---------------- pass 2: bucket prefix + per-bucket CSR offsets + placement -----
__global__ __launch_bounds__(512) void k_place(
    const unsigned int* __restrict__ region, const int* __restrict__ bucket_cnt,
    const int* __restrict__ ovf_cnt, const unsigned int* __restrict__ ovf,
    int* __restrict__ offs, int* __restrict__ esrc) {
    int b = blockIdx.x;
    int t = threadIdx.x;
    __shared__ int sb[256];
    __shared__ int hist[256], s[256], curs[256];

    if (t < 256) {
        sb[t] = (t < NBUCK) ? bucket_cnt[t] : 0;
        hist[t] = 0;
    }
    __syncthreads();
    // inclusive scan over bucket counts (every block does it; ~196 values)
    for (int d = 1; d < 256; d <<= 1) {
        int u = (t >= d && t < 256) ? sb[t - d] : 0;
        __syncthreads();
        if (t < 256) sb[t] += u;
        __syncthreads();
    }
    int truec = bucket_cnt[b];
    int base_b = sb[b] - truec;          // exclusive prefix for this bucket
    int rc = min(truec, BCAP);
    const unsigned int* reg = region + (size_t)b * BCAP;

    for (int i = t; i < rc; i += 512) atomicAdd(&hist[(reg[i] >> 16) & 255], 1);
    int no = 0;
    if (truec > BCAP) {                  // statistically never; correctness fallback
        no = *ovf_cnt;
        for (int i = t; i < no; i += 512)
            if ((int)(ovf[i] >> 24) == b) atomicAdd(&hist[(ovf[i] >> 16) & 255], 1);
    }
    __syncthreads();
    int h = (t < 256) ? hist[t] : 0;
    if (t < 256) s[t] = h;
    __syncthreads();
    for (int d = 1; d < 256; d <<= 1) {
        int u = (t >= d && t < 256) ? s[t - d] : 0;
        __syncthreads();
        if (t < 256) s[t] += u;
        __syncthreads();
    }
    if (t < 256) {
        int pos0 = base_b + s[t] - h;
        int node = b * 256 + t;
        if (node < N_NODES) offs[node] = pos0;
        curs[t] = pos0;
    }
    if (b == NBUCK - 1 && t == 0) offs[N_NODES] = N_EDGES;
    __syncthreads();
    for (int i = t; i < rc; i += 512) {
        unsigned int p = reg[i];
        int pos = atomicAdd(&curs[(p >> 16) & 255], 1);
        esrc[pos] = (int)(p & 0xffffu);
    }
    if (truec > BCAP) {
        for (int i = t; i < no; i += 512) {
            unsigned int p = ovf[i];
            if ((int)(p >> 24) == b) {
                int pos = atomicAdd(&curs[(p >> 16) & 255], 1);
                esrc[pos] = (int)(p & 0xffffu);
            }
        }
    }
}

// ---------------- aggregation: one wave per dst node ----------------
__global__ __launch_bounds__(256) void k_aggregate(
    const unsigned short* __restrict__ ftb, const float* __restrict__ a1,
    const float* __restrict__ a2, const int* __restrict__ offs,
    const int* __restrict__ esrc, float* __restrict__ out) {
    __shared__ float lw[4][DEG_CAP * N_HEADS];
    __shared__ int   ls[4][DEG_CAP];

    int wid  = threadIdx.x >> 6;
    int lane = threadIdx.x & 63;
    int node = blockIdx.x * 4 + wid;
    float* w  = lw[wid];
    int*   si = ls[wid];

    int off = offs[node];
    int deg = offs[node + 1] - off;

    // phase A: 8 edges x 8 heads per iteration; denom + cached exp weights
    int h1 = lane & 7;
    int es = lane >> 3;
    float a2h = a2[node * N_HEADS + h1];

    float l = 0.f;
    for (int base = 0; base < deg; base += 8) {
        int e = base + es;
        if (e < deg) {
            int s = esrc[off + e];
            float t = a1[s * N_HEADS + h1] + a2h;
            t = t > 0.f ? t : 0.2f * t;
            float ww = __expf(t);
            l += ww;
            if (e < DEG_CAP) {
                w[e * N_HEADS + h1] = ww;
                if (h1 == 0) si[e] = s;
            }
        }
    }
    l += __shfl_xor(l, 8);
    l += __shfl_xor(l, 16);
    l += __shfl_xor(l, 32);
    float invl = (deg > 0) ? 1.f / l : 0.f;

    int lim = min(deg, DEG_CAP);
    for (int e = es; e < lim; e += 8) w[e * N_HEADS + h1] *= invl;

    // phase B: 2 edges/iter; lanes 0-31 edge j, lanes 32-63 edge j+1.
    // lane sub covers dims [4*sub, 4*sub+4) via one uint2 (4 bf16).
    int sub = lane & 31;
    int e2  = lane >> 5;
    int hB  = sub >> 2;
    float invlB = __shfl(invl, hB);   // lane hB holds head hB's denom
    float a2hB  = __shfl(a2h, hB);

    float acc0 = 0.f, acc1 = 0.f, acc2 = 0.f, acc3 = 0.f;
    for (int j = 0; j < lim; j += 2) {
        int jj = j + e2;
        float ww = 0.f;
        int s = 0;
        if (jj < lim) { ww = w[jj * N_HEADS + hB]; s = si[jj]; }
        uint2 q = *(const uint2*)(ftb + (size_t)s * HD + sub * 4);
        acc0 = fmaf(ww, __uint_as_float(q.x << 16), acc0);
        acc1 = fmaf(ww, __uint_as_float(q.x & 0xffff0000u), acc1);
        acc2 = fmaf(ww, __uint_as_float(q.y << 16), acc2);
        acc3 = fmaf(ww, __uint_as_float(q.y & 0xffff0000u), acc3);
    }
    // fallback for deg > DEG_CAP (statistically never; correctness only)
    for (int j = DEG_CAP; j < deg; j += 2) {
        int jj = j + e2;
        float ww = 0.f;
        int s = 0;
        if (jj < deg) {
            s = esrc[off + jj];
            float t = a1[s * N_HEADS + hB] + a2hB;
            t = t > 0.f ? t : 0.2f * t;
            ww = __expf(t) * invlB;
        }
        uint2 q = *(const uint2*)(ftb + (size_t)s * HD + sub * 4);
        acc0 = fmaf(ww, __uint_as_float(q.x << 16), acc0);
        acc1 = fmaf(ww, __uint_as_float(q.x & 0xffff0000u), acc1);
        acc2 = fmaf(ww, __uint_as_float(q.y << 16), acc2);
        acc3 = fmaf(ww, __uint_as_float(q.y & 0xffff0000u), acc3);
    }

    acc0 += __shfl_xor(acc0, 32);
    acc1 += __shfl_xor(acc1, 32);
    acc2 += __shfl_xor(acc2, 32);
    acc3 += __shfl_xor(acc3, 32);
    if (lane < 32) {
        float4 o = make_float4(acc0, acc1, acc2, acc3);
        *(float4*)(out + (size_t)node * HD + sub * 4) = o;
    }
}

// ---------------- host launcher ----------------
extern "C" void kernel_launch(void* const* d_in, const int* in_sizes, int n_in,
                              void* d_out, int out_size, void* d_ws, size_t ws_size,
                              hipStream_t stream) {
    const float* x      = (const float*)d_in[0];
    const float* W      = (const float*)d_in[1];
    const float* attn_l = (const float*)d_in[2];
    const float* attn_r = (const float*)d_in[3];
    const int*   src    = (const int*)d_in[4];
    const int*   dst    = (const int*)d_in[5];
    float* out = (float*)d_out;

    char* ws = (char*)d_ws;
    size_t o = 0;
    auto alloc = [&](size_t bytes) -> char* {
        char* p = ws + o;
        o = (o + bytes + 255) & ~(size_t)255;
        return p;
    };
    unsigned short* ftb = (unsigned short*)alloc((size_t)N_NODES * HD * 2);
    float* a1          = (float*)alloc((size_t)N_NODES * N_HEADS * 4);
    float* a2          = (float*)alloc((size_t)N_NODES * N_HEADS * 4);
    float* Wt          = (float*)alloc((size_t)HD * IN_DIM * 4);
    unsigned int* region = (unsigned int*)alloc((size_t)NBUCK * BCAP * 4);
    int* bucket_cnt    = (int*)alloc((size_t)NBUCK * 4);
    int* ovf_cnt       = (int*)alloc(4);
    unsigned int* ovf  = (unsigned int*)alloc((size_t)N_EDGES * 4);
    int* offs          = (int*)alloc((size_t)(N_NODES + 1) * 4);
    int* esrc          = (int*)alloc((size_t)N_EDGES * 4);

    (void)in_sizes; (void)n_in; (void)out_size; (void)ws_size;

    k_transpose_w<<<16, 256, 0, stream>>>(W, Wt, bucket_cnt, ovf_cnt);
    k_project<<<(N_NODES + 31) / 32, 256, 0, stream>>>(x, Wt, attn_l, attn_r, ftb, a1, a2);
    k_bin<<<BIN_BLOCKS, 256, 0, stream>>>(src, dst, region, bucket_cnt, ovf_cnt, ovf);
    k_place<<<NBUCK, 512, 0, stream>>>(region, bucket_cnt, ovf_cnt, ovf, offs, esrc);
    k_aggregate<<<N_NODES / 4, 256, 0, stream>>>(ftb, a1, a2, offs, esrc, out);
}

// Round 5
// 233.118 us; speedup vs baseline: 1.1472x; 1.1472x over previous
//
#include <hip/hip_runtime.h>
#include <math.h>

#define N_NODES 50000
#define N_EDGES 1600000
#define IN_DIM 128
#define N_HEADS 8
#define OUT_DIM 16
#define HD 128            // N_HEADS * OUT_DIM
#define DEG_CAP 128       // LDS-cached edges per node in aggregate
#define NBUCK 196         // ceil(N_NODES / 256) coarse buckets (256 nodes each)
#define BCAP 12288        // region capacity per bucket (avg ~8163)
#define CHUNK 2048        // edges per bin block
#define BIN_BLOCKS ((N_EDGES + CHUNK - 1) / CHUNK)   // 782
#define PBLK ((N_NODES + 31) / 32)                    // 1563 projection blocks

__device__ __forceinline__ unsigned short f2bf(float f) {
    union { float f; unsigned int u; } v; v.f = f;
    unsigned int u = v.u;
    unsigned int r = (u + 0x7fffu + ((u >> 16) & 1u)) >> 16;   // RN-even
    return (unsigned short)r;
}

// ---------------- W transpose + zero bin state (one-time, fused) ----------------
__global__ void k_transpose_w(const float* __restrict__ W, float* __restrict__ Wt,
                              int* __restrict__ bucket_cnt, int* __restrict__ ovf_cnt) {
    if (blockIdx.x == 0) {
        int t = threadIdx.x;
        if (t < NBUCK) bucket_cnt[t] = 0;
        if (t == 0) *ovf_cnt = 0;
    }
    int flat4 = blockIdx.x * blockDim.x + threadIdx.x;
    if (flat4 >= (HD * IN_DIM) / 4) return;
    int c  = flat4 >> 5;
    int k4 = flat4 & 31;
    float4 v = ((const float4*)W)[flat4];
    int k = k4 * 4;
    Wt[(k + 0) * HD + c] = v.x;
    Wt[(k + 1) * HD + c] = v.y;
    Wt[(k + 2) * HD + c] = v.z;
    Wt[(k + 3) * HD + c] = v.w;
}

// ---------------- fused: projection (blocks < PBLK) | edge binning (rest) --------
// Independent stages; fusing overlaps FMA-heavy projection with LDS-atomic binning.
__global__ __launch_bounds__(256) void k_proj_bin(
    const float* __restrict__ x, const float* __restrict__ Wt,
    const float* __restrict__ attn_l, const float* __restrict__ attn_r,
    unsigned short* __restrict__ ftb, float* __restrict__ a1, float* __restrict__ a2,
    const int* __restrict__ src, const int* __restrict__ dst,
    unsigned int* __restrict__ region, int* __restrict__ bucket_cnt,
    int* __restrict__ ovf_cnt, unsigned int* __restrict__ ovf) {
    __shared__ __align__(16) char smem[13312];   // union: proj 8 KB | bin 13.3 KB
    int tid = threadIdx.x;

    if (blockIdx.x < PBLK) {
        // ---------------- projection branch ----------------
        float (*red_l)[32] = (float(*)[32])smem;
        float (*red_r)[32] = (float(*)[32])(smem + 4096);

        int cb = (tid & 31) * 4;
        int nb = (tid >> 5) * 4;
        int node0 = blockIdx.x * 32;

        float4 acc[4];
        acc[0] = acc[1] = acc[2] = acc[3] = make_float4(0.f, 0.f, 0.f, 0.f);

        const float* xrow[4];
#pragma unroll
        for (int i = 0; i < 4; i++) {
            int n = node0 + nb + i;
            if (n >= N_NODES) n = N_NODES - 1;
            xrow[i] = x + (size_t)n * IN_DIM;
        }

        for (int k = 0; k < IN_DIM; k += 4) {
            float4 w0 = *(const float4*)(Wt + (k + 0) * HD + cb);
            float4 w1 = *(const float4*)(Wt + (k + 1) * HD + cb);
            float4 w2 = *(const float4*)(Wt + (k + 2) * HD + cb);
            float4 w3 = *(const float4*)(Wt + (k + 3) * HD + cb);
#pragma unroll
            for (int i = 0; i < 4; i++) {
                float4 xv = *(const float4*)(xrow[i] + k);
                acc[i].x = fmaf(xv.w, w3.x, fmaf(xv.z, w2.x, fmaf(xv.y, w1.x, fmaf(xv.x, w0.x, acc[i].x))));
                acc[i].y = fmaf(xv.w, w3.y, fmaf(xv.z, w2.y, fmaf(xv.y, w1.y, fmaf(xv.x, w0.y, acc[i].y))));
                acc[i].z = fmaf(xv.w, w3.z, fmaf(xv.z, w2.z, fmaf(xv.y, w1.z, fmaf(xv.x, w0.z, acc[i].z))));
                acc[i].w = fmaf(xv.w, w3.w, fmaf(xv.z, w2.w, fmaf(xv.y, w1.w, fmaf(xv.x, w0.w, acc[i].w))));
            }
        }

#pragma unroll
        for (int i = 0; i < 4; i++) {
            int n = node0 + nb + i;
            if (n < N_NODES) {
                ushort4 us;
                us.x = f2bf(acc[i].x); us.y = f2bf(acc[i].y);
                us.z = f2bf(acc[i].z); us.w = f2bf(acc[i].w);
                *(ushort4*)(ftb + (size_t)n * HD + cb) = us;
            }
        }

        int h   = cb >> 4;
        int sub = cb & 15;
        float4 al = *(const float4*)(attn_l + h * OUT_DIM + sub);
        float4 ar = *(const float4*)(attn_r + h * OUT_DIM + sub);
        int col = (h << 2) | (sub >> 2);
#pragma unroll
        for (int i = 0; i < 4; i++) {
            float pl = acc[i].x * al.x + acc[i].y * al.y + acc[i].z * al.z + acc[i].w * al.w;
            float pr = acc[i].x * ar.x + acc[i].y * ar.y + acc[i].z * ar.z + acc[i].w * ar.w;
            red_l[nb + i][col] = pl;
            red_r[nb + i][col] = pr;
        }
        __syncthreads();
        int nl = tid >> 3, hh = tid & 7;
        int n = node0 + nl;
        if (n < N_NODES) {
            float s1 = red_l[nl][hh * 4 + 0] + red_l[nl][hh * 4 + 1] + red_l[nl][hh * 4 + 2] + red_l[nl][hh * 4 + 3];
            float s2 = red_r[nl][hh * 4 + 0] + red_r[nl][hh * 4 + 1] + red_r[nl][hh * 4 + 2] + red_r[nl][hh * 4 + 3];
            a1[n * N_HEADS + hh] = s1;
            a2[n * N_HEADS + hh] = s2;
        }
    } else {
        // ---------------- binning branch ----------------
        unsigned int* stage = (unsigned int*)smem;          // 8 KB
        int* hist  = (int*)(smem + 8192);
        int* scan  = (int*)(smem + 9216);
        int* loff  = (int*)(smem + 10240);
        int* lcur  = (int*)(smem + 11264);
        int* rbase = (int*)(smem + 12288);

        int t = tid;
        int base = (blockIdx.x - PBLK) * CHUNK;
        int nvalid = min(CHUNK, N_EDGES - base);

        hist[t] = 0;
        __syncthreads();

        unsigned int mypack[CHUNK / 256];
#pragma unroll
        for (int k = 0; k < CHUNK / 256; k++) {
            int i = t + k * 256;
            if (i < nvalid) {
                int s = src[base + i];
                int d = dst[base + i];
                unsigned int p = ((unsigned int)d << 16) | (unsigned int)s;
                mypack[k] = p;
                atomicAdd(&hist[d >> 8], 1);
            }
        }
        __syncthreads();
        int h = hist[t];
        scan[t] = h;
        __syncthreads();
        for (int d2 = 1; d2 < 256; d2 <<= 1) {
            int u = (t >= d2) ? scan[t - d2] : 0;
            __syncthreads();
            scan[t] += u;
            __syncthreads();
        }
        int excl = scan[t] - h;
        loff[t] = excl;
        lcur[t] = excl;
        rbase[t] = (t < NBUCK && h > 0) ? atomicAdd(&bucket_cnt[t], h) : 0;
        __syncthreads();
#pragma unroll
        for (int k = 0; k < CHUNK / 256; k++) {
            int i = t + k * 256;
            if (i < nvalid) {
                unsigned int p = mypack[k];
                int slot = atomicAdd(&lcur[p >> 24], 1);
                stage[slot] = p;
            }
        }
        __syncthreads();
        for (int i = t; i < nvalid; i += 256) {
            unsigned int p = stage[i];
            int b = p >> 24;
            int pos = rbase[b] + (i - loff[b]);
            if (pos < BCAP) region[(size_t)b * BCAP + pos] = p;
            else { int o = atomicAdd(ovf_cnt, 1); ovf[o] = p; }
        }
    }
}

// ---------------- bucket prefix + per-bucket CSR offsets + placement -----
__global__ __launch_bounds__(512) void k_place(
    const unsigned int* __restrict__ region, const int* __restrict__ bucket_cnt,
    const int* __restrict__ ovf_cnt, const unsigned int* __restrict__ ovf,
    int* __restrict__ offs, int* __restrict__ esrc) {
    int b = blockIdx.x;
    int t = threadIdx.x;
    __shared__ int sb[256];
    __shared__ int hist[256], s[256], curs[256];

    if (t < 256) {
        sb[t] = (t < NBUCK) ? bucket_cnt[t] : 0;
        hist[t] = 0;
    }
    __syncthreads();
    for (int d = 1; d < 256; d <<= 1) {
        int u = (t >= d && t < 256) ? sb[t - d] : 0;
        __syncthreads();
        if (t < 256) sb[t] += u;
        __syncthreads();
    }
    int truec = bucket_cnt[b];
    int base_b = sb[b] - truec;
    int rc = min(truec, BCAP);
    const unsigned int* reg = region + (size_t)b * BCAP;

    for (int i = t; i < rc; i += 512) atomicAdd(&hist[(reg[i] >> 16) & 255], 1);
    int no = 0;
    if (truec > BCAP) {                  // statistically never; correctness fallback
        no = *ovf_cnt;
        for (int i = t; i < no; i += 512)
            if ((int)(ovf[i] >> 24) == b) atomicAdd(&hist[(ovf[i] >> 16) & 255], 1);
    }
    __syncthreads();
    int h = (t < 256) ? hist[t] : 0;
    if (t < 256) s[t] = h;
    __syncthreads();
    for (int d = 1; d < 256; d <<= 1) {
        int u = (t >= d && t < 256) ? s[t - d] : 0;
        __syncthreads();
        if (t < 256) s[t] += u;
        __syncthreads();
    }
    if (t < 256) {
        int pos0 = base_b + s[t] - h;
        int node = b * 256 + t;
        if (node < N_NODES) offs[node] = pos0;
        curs[t] = pos0;
    }
    if (b == NBUCK - 1 && t == 0) offs[N_NODES] = N_EDGES;
    __syncthreads();
    for (int i = t; i < rc; i += 512) {
        unsigned int p = reg[i];
        int pos = atomicAdd(&curs[(p >> 16) & 255], 1);
        esrc[pos] = (int)(p & 0xffffu);
    }
    if (truec > BCAP) {
        for (int i = t; i < no; i += 512) {
            unsigned int p = ovf[i];
            if ((int)(p >> 24) == b) {
                int pos = atomicAdd(&curs[(p >> 16) & 255], 1);
                esrc[pos] = (int)(p & 0xffffu);
            }
        }
    }
}

// ---------------- aggregation: one wave per dst node ----------------
__global__ __launch_bounds__(256) void k_aggregate(
    const unsigned short* __restrict__ ftb, const float* __restrict__ a1,
    const float* __restrict__ a2, const int* __restrict__ offs,
    const int* __restrict__ esrc, float* __restrict__ out) {
    __shared__ float lw[4][DEG_CAP * N_HEADS];
    __shared__ int   ls[4][DEG_CAP];

    int wid  = threadIdx.x >> 6;
    int lane = threadIdx.x & 63;
    int node = blockIdx.x * 4 + wid;
    float* w  = lw[wid];
    int*   si = ls[wid];

    int off = offs[node];
    int deg = offs[node + 1] - off;

    // phase A: 8 edges x 8 heads per iteration; denom + cached exp weights
    int h1 = lane & 7;
    int es = lane >> 3;
    float a2h = a2[node * N_HEADS + h1];

    float l = 0.f;
    for (int base = 0; base < deg; base += 8) {
        int e = base + es;
        if (e < deg) {
            int s = esrc[off + e];
            float t = a1[s * N_HEADS + h1] + a2h;
            t = t > 0.f ? t : 0.2f * t;
            float ww = __expf(t);
            l += ww;
            if (e < DEG_CAP) {
                w[e * N_HEADS + h1] = ww;
                if (h1 == 0) si[e] = s;
            }
        }
    }
    l += __shfl_xor(l, 8);
    l += __shfl_xor(l, 16);
    l += __shfl_xor(l, 32);
    float invl = (deg > 0) ? 1.f / l : 0.f;

    int lim = min(deg, DEG_CAP);
    for (int e = es; e < lim; e += 8) w[e * N_HEADS + h1] *= invl;

    // phase B (round-3 mapping, deeper unroll): one edge per iter, whole wave
    // reads one 256 B ft row coalesced; lane covers dims {2*lane, 2*lane+1}.
    int hl = lane >> 3;
    float invl2 = __shfl(invl, hl);
    float a2h2  = __shfl(a2h, hl);

    float accx = 0.f, accy = 0.f;
#pragma unroll 8
    for (int j = 0; j < lim; j++) {
        float ww = w[j * N_HEADS + hl];
        int s = si[j];
        unsigned int p = *(const unsigned int*)(ftb + (size_t)s * HD + lane * 2);
        float fx = __uint_as_float(p << 16);
        float fy = __uint_as_float(p & 0xffff0000u);
        accx = fmaf(ww, fx, accx);
        accy = fmaf(ww, fy, accy);
    }
    // fallback for deg > DEG_CAP (statistically never; correctness only)
    for (int j = DEG_CAP; j < deg; j++) {
        int s = esrc[off + j];
        float t = a1[s * N_HEADS + hl] + a2h2;
        t = t > 0.f ? t : 0.2f * t;
        float ww = __expf(t) * invl2;
        unsigned int p = *(const unsigned int*)(ftb + (size_t)s * HD + lane * 2);
        accx = fmaf(ww, __uint_as_float(p << 16), accx);
        accy = fmaf(ww, __uint_as_float(p & 0xffff0000u), accy);
    }

    float2 o; o.x = accx; o.y = accy;
    *(float2*)(out + (size_t)node * HD + lane * 2) = o;
}

// ---------------- host launcher ----------------
extern "C" void kernel_launch(void* const* d_in, const int* in_sizes, int n_in,
                              void* d_out, int out_size, void* d_ws, size_t ws_size,
                              hipStream_t stream) {
    const float* x      = (const float*)d_in[0];
    const float* W      = (const float*)d_in[1];
    const float* attn_l = (const float*)d_in[2];
    const float* attn_r = (const float*)d_in[3];
    const int*   src    = (const int*)d_in[4];
    const int*   dst    = (const int*)d_in[5];
    float* out = (float*)d_out;

    char* ws = (char*)d_ws;
    size_t o = 0;
    auto alloc = [&](size_t bytes) -> char* {
        char* p = ws + o;
        o = (o + bytes + 255) & ~(size_t)255;
        return p;
    };
    unsigned short* ftb = (unsigned short*)alloc((size_t)N_NODES * HD * 2);
    float* a1          = (float*)alloc((size_t)N_NODES * N_HEADS * 4);
    float* a2          = (float*)alloc((size_t)N_NODES * N_HEADS * 4);
    float* Wt          = (float*)alloc((size_t)HD * IN_DIM * 4);
    unsigned int* region = (unsigned int*)alloc((size_t)NBUCK * BCAP * 4);
    int* bucket_cnt    = (int*)alloc((size_t)NBUCK * 4);
    int* ovf_cnt       = (int*)alloc(4);
    unsigned int* ovf  = (unsigned int*)alloc((size_t)N_EDGES * 4);
    int* offs          = (int*)alloc((size_t)(N_NODES + 1) * 4);
    int* esrc          = (int*)alloc((size_t)N_EDGES * 4);

    (void)in_sizes; (void)n_in; (void)out_size; (void)ws_size;

    k_transpose_w<<<16, 256, 0, stream>>>(W, Wt, bucket_cnt, ovf_cnt);
    k_proj_bin<<<PBLK + BIN_BLOCKS, 256, 0, stream>>>(
        x, Wt, attn_l, attn_r, ftb, a1, a2,
        src, dst, region, bucket_cnt, ovf_cnt, ovf);
    k_place<<<NBUCK, 512, 0, stream>>>(region, bucket_cnt, ovf_cnt, ovf, offs, esrc);
    k_aggregate<<<N_NODES / 4, 256, 0, stream>>>(ftb, a1, a2, offs, esrc, out);
}

// Round 6
// 229.371 us; speedup vs baseline: 1.1659x; 1.0163x over previous
//
#include <hip/hip_runtime.h>
#include <math.h>

#define N_NODES 50000
#define N_EDGES 1600000
#define IN_DIM 128
#define N_HEADS 8
#define OUT_DIM 16
#define HD 128            // N_HEADS * OUT_DIM
#define DEG_CAP 128       // LDS-cached edges per node in aggregate
#define NBUCK 784         // dst>>6: 64 nodes per bucket
#define BCAP 2560         // region capacity per bucket (avg ~2041)
#define CHUNK 4096        // edges per bin block
#define BIN_BLOCKS ((N_EDGES + CHUNK - 1) / CHUNK)   // 391
#define PBLK ((N_NODES + 31) / 32)                    // 1563 projection blocks

__device__ __forceinline__ unsigned short f2bf(float f) {
    union { float f; unsigned int u; } v; v.f = f;
    unsigned int u = v.u;
    unsigned int r = (u + 0x7fffu + ((u >> 16) & 1u)) >> 16;   // RN-even
    return (unsigned short)r;
}

// exclusive scan of arr[0..NBUCK) in place; part[256] scratch; all 256 threads.
__device__ __forceinline__ void scan_nbuck_excl(int* arr, int* part) {
    int t = threadIdx.x;
    int v0 = 0, v1 = 0, v2 = 0, v3 = 0, cs = 0;
    if (t < NBUCK / 4) {            // 196 active, 4 values each
        v0 = arr[4 * t]; v1 = arr[4 * t + 1]; v2 = arr[4 * t + 2]; v3 = arr[4 * t + 3];
        cs = v0 + v1 + v2 + v3;
    }
    part[t] = cs;
    __syncthreads();
    for (int d = 1; d < 256; d <<= 1) {
        int u = (t >= d) ? part[t - d] : 0;
        __syncthreads();
        part[t] += u;
        __syncthreads();
    }
    if (t < NBUCK / 4) {
        int run = part[t] - cs;
        arr[4 * t] = run; run += v0;
        arr[4 * t + 1] = run; run += v1;
        arr[4 * t + 2] = run; run += v2;
        arr[4 * t + 3] = run;
    }
    __syncthreads();
}

// ---------------- W transpose + zero bin state (one-time, fused) ----------------
__global__ void k_transpose_w(const float* __restrict__ W, float* __restrict__ Wt,
                              int* __restrict__ bucket_cnt, int* __restrict__ ovf_cnt) {
    int g = blockIdx.x * 256 + threadIdx.x;
    if (g < NBUCK) bucket_cnt[g] = 0;
    if (g == 0) *ovf_cnt = 0;
    if (g >= (HD * IN_DIM) / 4) return;
    int c  = g >> 5;
    int k4 = g & 31;
    float4 v = ((const float4*)W)[g];
    int k = k4 * 4;
    Wt[(k + 0) * HD + c] = v.x;
    Wt[(k + 1) * HD + c] = v.y;
    Wt[(k + 2) * HD + c] = v.z;
    Wt[(k + 3) * HD + c] = v.w;
}

// ---------------- fused: projection (blocks < PBLK) | edge binning (rest) --------
__global__ __launch_bounds__(256, 2) void k_proj_bin(
    const float* __restrict__ x, const float* __restrict__ Wt,
    const float* __restrict__ attn_l, const float* __restrict__ attn_r,
    unsigned short* __restrict__ ftb, float* __restrict__ a1, float* __restrict__ a2,
    const int* __restrict__ src, const int* __restrict__ dst,
    unsigned int* __restrict__ region, int* __restrict__ bucket_cnt,
    int* __restrict__ ovf_cnt, unsigned int* __restrict__ ovf) {
    // union: proj red_l/red_r 8 KB | bin stage 16 KB + hist 3136 + delta 3136 + part 1024
    __shared__ __align__(16) char smem[23680];
    int tid = threadIdx.x;

    if (blockIdx.x < PBLK) {
        // ---------------- projection branch ----------------
        float (*red_l)[32] = (float(*)[32])smem;
        float (*red_r)[32] = (float(*)[32])(smem + 4096);

        int cb = (tid & 31) * 4;
        int nb = (tid >> 5) * 4;
        int node0 = blockIdx.x * 32;

        float4 acc[4];
        acc[0] = acc[1] = acc[2] = acc[3] = make_float4(0.f, 0.f, 0.f, 0.f);

        const float* xrow[4];
#pragma unroll
        for (int i = 0; i < 4; i++) {
            int n = node0 + nb + i;
            if (n >= N_NODES) n = N_NODES - 1;
            xrow[i] = x + (size_t)n * IN_DIM;
        }

#pragma unroll 2
        for (int k = 0; k < IN_DIM; k += 4) {
            float4 w0 = *(const float4*)(Wt + (k + 0) * HD + cb);
            float4 w1 = *(const float4*)(Wt + (k + 1) * HD + cb);
            float4 w2 = *(const float4*)(Wt + (k + 2) * HD + cb);
            float4 w3 = *(const float4*)(Wt + (k + 3) * HD + cb);
#pragma unroll
            for (int i = 0; i < 4; i++) {
                float4 xv = *(const float4*)(xrow[i] + k);
                acc[i].x = fmaf(xv.w, w3.x, fmaf(xv.z, w2.x, fmaf(xv.y, w1.x, fmaf(xv.x, w0.x, acc[i].x))));
                acc[i].y = fmaf(xv.w, w3.y, fmaf(xv.z, w2.y, fmaf(xv.y, w1.y, fmaf(xv.x, w0.y, acc[i].y))));
                acc[i].z = fmaf(xv.w, w3.z, fmaf(xv.z, w2.z, fmaf(xv.y, w1.z, fmaf(xv.x, w0.z, acc[i].z))));
                acc[i].w = fmaf(xv.w, w3.w, fmaf(xv.z, w2.w, fmaf(xv.y, w1.w, fmaf(xv.x, w0.w, acc[i].w))));
            }
        }

#pragma unroll
        for (int i = 0; i < 4; i++) {
            int n = node0 + nb + i;
            if (n < N_NODES) {
                ushort4 us;
                us.x = f2bf(acc[i].x); us.y = f2bf(acc[i].y);
                us.z = f2bf(acc[i].z); us.w = f2bf(acc[i].w);
                *(ushort4*)(ftb + (size_t)n * HD + cb) = us;
            }
        }

        int h   = cb >> 4;
        int sub = cb & 15;
        float4 al = *(const float4*)(attn_l + h * OUT_DIM + sub);
        float4 ar = *(const float4*)(attn_r + h * OUT_DIM + sub);
        int col = (h << 2) | (sub >> 2);
#pragma unroll
        for (int i = 0; i < 4; i++) {
            float pl = acc[i].x * al.x + acc[i].y * al.y + acc[i].z * al.z + acc[i].w * al.w;
            float pr = acc[i].x * ar.x + acc[i].y * ar.y + acc[i].z * ar.z + acc[i].w * ar.w;
            red_l[nb + i][col] = pl;
            red_r[nb + i][col] = pr;
        }
        __syncthreads();
        int nl = tid >> 3, hh = tid & 7;
        int n = node0 + nl;
        if (n < N_NODES) {
            float s1 = red_l[nl][hh * 4 + 0] + red_l[nl][hh * 4 + 1] + red_l[nl][hh * 4 + 2] + red_l[nl][hh * 4 + 3];
            float s2 = red_r[nl][hh * 4 + 0] + red_r[nl][hh * 4 + 1] + red_r[nl][hh * 4 + 2] + red_r[nl][hh * 4 + 3];
            a1[n * N_HEADS + hh] = s1;
            a2[n * N_HEADS + hh] = s2;
        }
    } else {
        // ---------------- binning branch ----------------
        unsigned int* stage = (unsigned int*)smem;          // 16 KB
        int* hist  = (int*)(smem + 16384);                  // NBUCK
        int* delta = (int*)(smem + 19520);                  // NBUCK
        int* part  = (int*)(smem + 22656);                  // 256

        int t = tid;
        int base = (blockIdx.x - PBLK) * CHUNK;
        int nvalid = min(CHUNK, N_EDGES - base);

        for (int i = t; i < NBUCK; i += 256) hist[i] = 0;
        __syncthreads();

        unsigned int mypack[CHUNK / 256];
#pragma unroll
        for (int k = 0; k < CHUNK / 256; k++) {
            int i = t + k * 256;
            if (i < nvalid) {
                int s = src[base + i];
                int d = dst[base + i];
                unsigned int p = ((unsigned int)d << 16) | (unsigned int)s;
                mypack[k] = p;
                atomicAdd(&hist[d >> 6], 1);
            }
        }
        __syncthreads();
        // reserve global runs; stash run base in delta
        for (int i = t; i < NBUCK; i += 256) {
            int h = hist[i];
            delta[i] = (h > 0) ? atomicAdd(&bucket_cnt[i], h) : 0;
        }
        __syncthreads();
        scan_nbuck_excl(hist, part);            // hist -> local exclusive offsets (loff)
        for (int i = t; i < NBUCK; i += 256) delta[i] -= hist[i];   // rb - loff
        __syncthreads();
        // local bucket sort into stage (hist doubles as cursor from loff)
#pragma unroll
        for (int k = 0; k < CHUNK / 256; k++) {
            int i = t + k * 256;
            if (i < nvalid) {
                unsigned int p = mypack[k];
                int slot = atomicAdd(&hist[p >> 22], 1);
                stage[slot] = p;
            }
        }
        __syncthreads();
        // write contiguous runs: global in-bucket pos = delta[b] + stage_index
        for (int i = t; i < nvalid; i += 256) {
            unsigned int p = stage[i];
            int b = p >> 22;
            int pos = delta[b] + i;
            if (pos < BCAP) region[(size_t)b * BCAP + pos] = p;
            else { int o = atomicAdd(ovf_cnt, 1); ovf[o] = p; }
        }
    }
}

// ---------------- per-bucket CSR offsets + placement (784-way parallel) ----------
__global__ __launch_bounds__(256) void k_place(
    const unsigned int* __restrict__ region, const int* __restrict__ bucket_cnt,
    const int* __restrict__ ovf_cnt, const unsigned int* __restrict__ ovf,
    int* __restrict__ offs, int* __restrict__ esrc) {
    int b = blockIdx.x;
    int t = threadIdx.x;
    __shared__ int sb[NBUCK], part[256];
    __shared__ int hist[64], sc[64], curs[64];

    for (int i = t; i < NBUCK; i += 256) sb[i] = bucket_cnt[i];
    if (t < 64) hist[t] = 0;
    __syncthreads();
    scan_nbuck_excl(sb, part);            // sb -> exclusive bucket prefix

    int truec = bucket_cnt[b];
    int base_b = sb[b];
    int rc = min(truec, BCAP);
    const unsigned int* reg = region + (size_t)b * BCAP;

    for (int i = t; i < rc; i += 256) atomicAdd(&hist[(reg[i] >> 16) & 63], 1);
    int no = 0;
    if (truec > BCAP) {                   // statistically never; correctness fallback
        no = *ovf_cnt;
        for (int i = t; i < no; i += 256)
            if ((int)(ovf[i] >> 22) == b) atomicAdd(&hist[(ovf[i] >> 16) & 63], 1);
    }
    __syncthreads();
    int h = (t < 64) ? hist[t] : 0;
    if (t < 64) sc[t] = h;
    __syncthreads();
    for (int d = 1; d < 64; d <<= 1) {
        int u = (t >= d && t < 64) ? sc[t - d] : 0;
        __syncthreads();
        if (t < 64) sc[t] += u;
        __syncthreads();
    }
    if (t < 64) {
        int pos0 = base_b + sc[t] - h;
        int node = b * 64 + t;
        if (node < N_NODES) offs[node] = pos0;
        curs[t] = pos0;
    }
    if (b == 0 && t == 0) offs[N_NODES] = N_EDGES;
    __syncthreads();
    for (int i = t; i < rc; i += 256) {
        unsigned int p = reg[i];
        int pos = atomicAdd(&curs[(p >> 16) & 63], 1);
        esrc[pos] = (int)(p & 0xffffu);
    }
    if (truec > BCAP) {
        for (int i = t; i < no; i += 256) {
            unsigned int p = ovf[i];
            if ((int)(p >> 22) == b) {
                int pos = atomicAdd(&curs[(p >> 16) & 63], 1);
                esrc[pos] = (int)(p & 0xffffu);
            }
        }
    }
}

// ---------------- aggregation: one wave per dst node ----------------
__global__ __launch_bounds__(256) void k_aggregate(
    const unsigned short* __restrict__ ftb, const float* __restrict__ a1,
    const float* __restrict__ a2, const int* __restrict__ offs,
    const int* __restrict__ esrc, float* __restrict__ out) {
    __shared__ float lw[4][DEG_CAP * N_HEADS];
    __shared__ int   ls[4][DEG_CAP];

    int wid  = threadIdx.x >> 6;
    int lane = threadIdx.x & 63;
    int node = blockIdx.x * 4 + wid;
    float* w  = lw[wid];
    int*   si = ls[wid];

    int off = offs[node];
    int deg = offs[node + 1] - off;

    // phase A: 8 edges x 8 heads per iteration; denom + cached exp weights
    int h1 = lane & 7;
    int es = lane >> 3;
    float a2h = a2[node * N_HEADS + h1];

    float l = 0.f;
    for (int base = 0; base < deg; base += 8) {
        int e = base + es;
        if (e < deg) {
            int s = esrc[off + e];
            float t = a1[s * N_HEADS + h1] + a2h;
            t = t > 0.f ? t : 0.2f * t;
            float ww = __expf(t);
            l += ww;
            if (e < DEG_CAP) {
                w[e * N_HEADS + h1] = ww;
                if (h1 == 0) si[e] = s;
            }
        }
    }
    l += __shfl_xor(l, 8);
    l += __shfl_xor(l, 16);
    l += __shfl_xor(l, 32);
    float invl = (deg > 0) ? 1.f / l : 0.f;

    int lim = min(deg, DEG_CAP);
    for (int e = es; e < lim; e += 8) w[e * N_HEADS + h1] *= invl;

    // phase B: one edge per iter, whole wave reads one 256 B ft row coalesced
    int hl = lane >> 3;
    float invl2 = __shfl(invl, hl);
    float a2h2  = __shfl(a2h, hl);

    float accx = 0.f, accy = 0.f;
#pragma unroll 8
    for (int j = 0; j < lim; j++) {
        float ww = w[j * N_HEADS + hl];
        int s = si[j];
        unsigned int p = *(const unsigned int*)(ftb + (size_t)s * HD + lane * 2);
        float fx = __uint_as_float(p << 16);
        float fy = __uint_as_float(p & 0xffff0000u);
        accx = fmaf(ww, fx, accx);
        accy = fmaf(ww, fy, accy);
    }
    for (int j = DEG_CAP; j < deg; j++) {   // statistically never; correctness only
        int s = esrc[off + j];
        float t = a1[s * N_HEADS + hl] + a2h2;
        t = t > 0.f ? t : 0.2f * t;
        float ww = __expf(t) * invl2;
        unsigned int p = *(const unsigned int*)(ftb + (size_t)s * HD + lane * 2);
        accx = fmaf(ww, __uint_as_float(p << 16), accx);
        accy = fmaf(ww, __uint_as_float(p & 0xffff0000u), accy);
    }

    float2 o; o.x = accx; o.y = accy;
    *(float2*)(out + (size_t)node * HD + lane * 2) = o;
}

// ---------------- host launcher ----------------
extern "C" void kernel_launch(void* const* d_in, const int* in_sizes, int n_in,
                              void* d_out, int out_size, void* d_ws, size_t ws_size,
                              hipStream_t stream) {
    const float* x      = (const float*)d_in[0];
    const float* W      = (const float*)d_in[1];
    const float* attn_l = (const float*)d_in[2];
    const float* attn_r = (const float*)d_in[3];
    const int*   src    = (const int*)d_in[4];
    const int*   dst    = (const int*)d_in[5];
    float* out = (float*)d_out;

    char* ws = (char*)d_ws;
    size_t o = 0;
    auto alloc = [&](size_t bytes) -> char* {
        char* p = ws + o;
        o = (o + bytes + 255) & ~(size_t)255;
        return p;
    };
    unsigned short* ftb = (unsigned short*)alloc((size_t)N_NODES * HD * 2);   // 12.8 MB
    float* a1          = (float*)alloc((size_t)N_NODES * N_HEADS * 4);
    float* a2          = (float*)alloc((size_t)N_NODES * N_HEADS * 4);
    float* Wt          = (float*)alloc((size_t)HD * IN_DIM * 4);
    unsigned int* region = (unsigned int*)alloc((size_t)NBUCK * BCAP * 4);    // 8.0 MB
    int* bucket_cnt    = (int*)alloc((size_t)NBUCK * 4);
    int* ovf_cnt       = (int*)alloc(4);
    unsigned int* ovf  = (unsigned int*)alloc((size_t)N_EDGES * 4);           // 6.4 MB
    int* offs          = (int*)alloc((size_t)(N_NODES + 1) * 4);
    int* esrc          = (int*)alloc((size_t)N_EDGES * 4);                    // 6.4 MB

    (void)in_sizes; (void)n_in; (void)out_size; (void)ws_size;

    k_transpose_w<<<16, 256, 0, stream>>>(W, Wt, bucket_cnt, ovf_cnt);
    k_proj_bin<<<PBLK + BIN_BLOCKS, 256, 0, stream>>>(
        x, Wt, attn_l, attn_r, ftb, a1, a2,
        src, dst, region, bucket_cnt, ovf_cnt, ovf);
    k_place<<<NBUCK, 256, 0, stream>>>(region, bucket_cnt, ovf_cnt, ovf, offs, esrc);
    k_aggregate<<<N_NODES / 4, 256, 0, stream>>>(ftb, a1, a2, offs, esrc, out);
}

// Round 7
// 209.018 us; speedup vs baseline: 1.2795x; 1.0974x over previous
//
#include <hip/hip_runtime.h>
#include <math.h>

#define N_NODES 50000
#define N_EDGES 1600000
#define IN_DIM 128
#define N_HEADS 8
#define OUT_DIM 16
#define HD 128            // N_HEADS * OUT_DIM
#define DEG_CAP 128       // LDS-cached edges per node in aggregate
#define NBUCK 784         // dst>>6: 64 nodes per bucket
#define BCAP 2560         // region capacity per bucket (avg ~2041)
#define CHUNK 4096        // edges per bin block
#define BIN_BLOCKS ((N_EDGES + CHUNK - 1) / CHUNK)   // 391
#define NTILE 3125        // 50000/16 M-tiles (exact)
#define PBLK ((NTILE + 3) / 4)                        // 782 proj blocks (4 waves each)
#define TROW 132          // LDS tile row stride in floats (128 + 4 pad)

typedef __attribute__((ext_vector_type(8))) short bf16x8;
typedef __attribute__((ext_vector_type(4))) float f32x4;

__device__ __forceinline__ unsigned short f2bf(float f) {
    union { float f; unsigned int u; } v; v.f = f;
    unsigned int u = v.u;
    unsigned int r = (u + 0x7fffu + ((u >> 16) & 1u)) >> 16;   // RN-even
    return (unsigned short)r;
}

// exclusive scan of arr[0..NBUCK) in place; part[256] scratch; all 256 threads.
__device__ __forceinline__ void scan_nbuck_excl(int* arr, int* part) {
    int t = threadIdx.x;
    int v0 = 0, v1 = 0, v2 = 0, v3 = 0, cs = 0;
    if (t < NBUCK / 4) {
        v0 = arr[4 * t]; v1 = arr[4 * t + 1]; v2 = arr[4 * t + 2]; v3 = arr[4 * t + 3];
        cs = v0 + v1 + v2 + v3;
    }
    part[t] = cs;
    __syncthreads();
    for (int d = 1; d < 256; d <<= 1) {
        int u = (t >= d) ? part[t - d] : 0;
        __syncthreads();
        part[t] += u;
        __syncthreads();
    }
    if (t < NBUCK / 4) {
        int run = part[t] - cs;
        arr[4 * t] = run; run += v0;
        arr[4 * t + 1] = run; run += v1;
        arr[4 * t + 2] = run; run += v2;
        arr[4 * t + 3] = run;
    }
    __syncthreads();
}

// ---------------- prep: W(f32) -> Wb(bf16, same [c][k] layout) + zero counters ----
__global__ void k_prep(const float* __restrict__ W, unsigned short* __restrict__ Wb,
                       int* __restrict__ bucket_cnt, int* __restrict__ ovf_cnt) {
    int g = blockIdx.x * 256 + threadIdx.x;   // 4096 threads over 4096 float4s
    if (g < NBUCK) bucket_cnt[g] = 0;
    if (g == 0) *ovf_cnt = 0;
    if (g >= (HD * IN_DIM) / 4) return;
    float4 v = ((const float4*)W)[g];
    ushort4 us;
    us.x = f2bf(v.x); us.y = f2bf(v.y); us.z = f2bf(v.z); us.w = f2bf(v.w);
    ((ushort4*)Wb)[g] = us;
}

// ---------------- fused: MFMA projection (blocks < PBLK) | edge binning ----------
__global__ __launch_bounds__(256) void k_proj_bin(
    const float* __restrict__ x, const unsigned short* __restrict__ Wb,
    const float* __restrict__ attn_l, const float* __restrict__ attn_r,
    unsigned short* __restrict__ ftb, float* __restrict__ a1, float* __restrict__ a2,
    const int* __restrict__ src, const int* __restrict__ dst,
    unsigned int* __restrict__ region, int* __restrict__ bucket_cnt,
    int* __restrict__ ovf_cnt, unsigned int* __restrict__ ovf) {
    // union: proj 4 wave-private f32 tiles 16x132 (33792 B) | bin 23680 B
    __shared__ __align__(16) char smem[4 * 16 * TROW * 4];
    int tid = threadIdx.x;

    if (blockIdx.x < PBLK) {
        // ---------------- MFMA projection branch ----------------
        int wid  = tid >> 6;
        int tile = blockIdx.x * 4 + wid;
        if (tile >= NTILE) return;           // no barriers in this branch
        int lane = tid & 63;
        int m = lane & 15, q = lane >> 4;
        int node0 = tile * 16;

        // A fragments: x[node0+m][ks*32 + q*8 .. +7], fp32 -> bf16
        const float* xr = x + (size_t)(node0 + m) * IN_DIM + q * 8;
        float4 xa[4][2];
#pragma unroll
        for (int ks = 0; ks < 4; ks++) {
            xa[ks][0] = *(const float4*)(xr + ks * 32);
            xa[ks][1] = *(const float4*)(xr + ks * 32 + 4);
        }
        bf16x8 afr[4];
#pragma unroll
        for (int ks = 0; ks < 4; ks++) {
            afr[ks][0] = (short)f2bf(xa[ks][0].x); afr[ks][1] = (short)f2bf(xa[ks][0].y);
            afr[ks][2] = (short)f2bf(xa[ks][0].z); afr[ks][3] = (short)f2bf(xa[ks][0].w);
            afr[ks][4] = (short)f2bf(xa[ks][1].x); afr[ks][5] = (short)f2bf(xa[ks][1].y);
            afr[ks][6] = (short)f2bf(xa[ks][1].z); afr[ks][7] = (short)f2bf(xa[ks][1].w);
        }

        float* tl = (float*)smem + wid * (16 * TROW);

        // heads loop: B frag = Wb[h*16+m][ks*32 + q*8 .. +7] (original W layout!)
#pragma unroll
        for (int h = 0; h < N_HEADS; h++) {
            const unsigned short* wrow = Wb + (size_t)(h * 16 + m) * IN_DIM + q * 8;
            f32x4 c = {0.f, 0.f, 0.f, 0.f};
#pragma unroll
            for (int ks = 0; ks < 4; ks++) {
                bf16x8 bfr = *(const bf16x8*)(wrow + ks * 32);
                c = __builtin_amdgcn_mfma_f32_16x16x32_bf16(afr[ks], bfr, c, 0, 0, 0);
            }
            // C layout: col = lane&15, row = q*4 + reg  -> stash in LDS tile
#pragma unroll
            for (int r = 0; r < 4; r++)
                tl[(q * 4 + r) * TROW + h * 16 + m] = c[r];
        }

        // a1/a2: lane -> node (lane&15), heads {lane>>4, (lane>>4)+4}
        int nd = lane & 15;
#pragma unroll
        for (int hi = 0; hi < 2; hi++) {
            int hh = (lane >> 4) + hi * 4;
            const float4* rowv = (const float4*)(tl + nd * TROW + hh * 16);
            const float4* alv  = (const float4*)(attn_l + hh * OUT_DIM);
            const float4* arv  = (const float4*)(attn_r + hh * OUT_DIM);
            float sl = 0.f, sr = 0.f;
#pragma unroll
            for (int d4 = 0; d4 < 4; d4++) {
                float4 fv = rowv[d4];
                float4 al = alv[d4];
                float4 ar = arv[d4];
                sl += fv.x * al.x + fv.y * al.y + fv.z * al.z + fv.w * al.w;
                sr += fv.x * ar.x + fv.y * ar.y + fv.z * ar.z + fv.w * ar.w;
            }
            a1[(node0 + nd) * N_HEADS + hh] = sl;
            a2[(node0 + nd) * N_HEADS + hh] = sr;
        }

        // ft store: pass p covers rows p*4+q; lane m covers 8 cols
#pragma unroll
        for (int p = 0; p < 4; p++) {
            int r = p * 4 + q;
            const float* srcp = tl + r * TROW + m * 8;
            float4 f0 = *(const float4*)(srcp);
            float4 f1 = *(const float4*)(srcp + 4);
            ushort4 u0, u1;
            u0.x = f2bf(f0.x); u0.y = f2bf(f0.y); u0.z = f2bf(f0.z); u0.w = f2bf(f0.w);
            u1.x = f2bf(f1.x); u1.y = f2bf(f1.y); u1.z = f2bf(f1.z); u1.w = f2bf(f1.w);
            ushort4* dstp = (ushort4*)(ftb + (size_t)(node0 + r) * HD + m * 8);
            dstp[0] = u0;
            dstp[1] = u1;
        }
    } else {
        // ---------------- binning branch ----------------
        unsigned int* stage = (unsigned int*)smem;          // 16 KB
        int* hist  = (int*)(smem + 16384);                  // NBUCK
        int* delta = (int*)(smem + 19520);                  // NBUCK
        int* part  = (int*)(smem + 22656);                  // 256

        int t = tid;
        int base = (blockIdx.x - PBLK) * CHUNK;
        int nvalid = min(CHUNK, N_EDGES - base);

        for (int i = t; i < NBUCK; i += 256) hist[i] = 0;
        __syncthreads();

        unsigned int mypack[CHUNK / 256];
#pragma unroll
        for (int k = 0; k < CHUNK / 256; k++) {
            int i = t + k * 256;
            if (i < nvalid) {
                int s = src[base + i];
                int d = dst[base + i];
                unsigned int p = ((unsigned int)d << 16) | (unsigned int)s;
                mypack[k] = p;
                atomicAdd(&hist[d >> 6], 1);
            }
        }
        __syncthreads();
        for (int i = t; i < NBUCK; i += 256) {
            int h = hist[i];
            delta[i] = (h > 0) ? atomicAdd(&bucket_cnt[i], h) : 0;
        }
        __syncthreads();
        scan_nbuck_excl(hist, part);            // hist -> local exclusive offsets
        for (int i = t; i < NBUCK; i += 256) delta[i] -= hist[i];
        __syncthreads();
#pragma unroll
        for (int k = 0; k < CHUNK / 256; k++) {
            int i = t + k * 256;
            if (i < nvalid) {
                unsigned int p = mypack[k];
                int slot = atomicAdd(&hist[p >> 22], 1);
                stage[slot] = p;
            }
        }
        __syncthreads();
        for (int i = t; i < nvalid; i += 256) {
            unsigned int p = stage[i];
            int b = p >> 22;
            int pos = delta[b] + i;
            if (pos < BCAP) region[(size_t)b * BCAP + pos] = p;
            else { int o = atomicAdd(ovf_cnt, 1); ovf[o] = p; }
        }
    }
}

// ---------------- per-bucket CSR offsets + placement (784-way parallel) ----------
__global__ __launch_bounds__(256) void k_place(
    const unsigned int* __restrict__ region, const int* __restrict__ bucket_cnt,
    const int* __restrict__ ovf_cnt, const unsigned int* __restrict__ ovf,
    int* __restrict__ offs, unsigned short* __restrict__ esrc) {
    int b = blockIdx.x;
    int t = threadIdx.x;
    __shared__ int sb[NBUCK], part[256];
    __shared__ int hist[64], sc[64], curs[64];

    for (int i = t; i < NBUCK; i += 256) sb[i] = bucket_cnt[i];
    if (t < 64) hist[t] = 0;
    __syncthreads();
    scan_nbuck_excl(sb, part);            // sb -> exclusive bucket prefix

    int truec = bucket_cnt[b];
    int base_b = sb[b];
    int rc = min(truec, BCAP);
    const unsigned int* reg = region + (size_t)b * BCAP;

    for (int i = t; i < rc; i += 256) atomicAdd(&hist[(reg[i] >> 16) & 63], 1);
    int no = 0;
    if (truec > BCAP) {                   // statistically never; correctness fallback
        no = *ovf_cnt;
        for (int i = t; i < no; i += 256)
            if ((int)(ovf[i] >> 22) == b) atomicAdd(&hist[(ovf[i] >> 16) & 63], 1);
    }
    __syncthreads();
    int h = (t < 64) ? hist[t] : 0;
    if (t < 64) sc[t] = h;
    __syncthreads();
    for (int d = 1; d < 64; d <<= 1) {
        int u = (t >= d && t < 64) ? sc[t - d] : 0;
        __syncthreads();
        if (t < 64) sc[t] += u;
        __syncthreads();
    }
    if (t < 64) {
        int pos0 = base_b + sc[t] - h;
        int node = b * 64 + t;
        if (node < N_NODES) offs[node] = pos0;
        curs[t] = pos0;
    }
    if (b == 0 && t == 0) offs[N_NODES] = N_EDGES;
    __syncthreads();
    for (int i = t; i < rc; i += 256) {
        unsigned int p = reg[i];
        int pos = atomicAdd(&curs[(p >> 16) & 63], 1);
        esrc[pos] = (unsigned short)(p & 0xffffu);
    }
    if (truec > BCAP) {
        for (int i = t; i < no; i += 256) {
            unsigned int p = ovf[i];
            if ((int)(p >> 22) == b) {
                int pos = atomicAdd(&curs[(p >> 16) & 63], 1);
                esrc[pos] = (unsigned short)(p & 0xffffu);
            }
        }
    }
}

// ---------------- aggregation: one wave per dst node ----------------
__global__ __launch_bounds__(256) void k_aggregate(
    const unsigned short* __restrict__ ftb, const float* __restrict__ a1,
    const float* __restrict__ a2, const int* __restrict__ offs,
    const unsigned short* __restrict__ esrc, float* __restrict__ out) {
    __shared__ float lw[4][DEG_CAP * N_HEADS];
    __shared__ int   ls[4][DEG_CAP];

    int wid  = threadIdx.x >> 6;
    int lane = threadIdx.x & 63;
    int node = blockIdx.x * 4 + wid;
    float* w  = lw[wid];
    int*   si = ls[wid];

    int off = offs[node];
    int deg = offs[node + 1] - off;

    // phase A: 8 edges x 8 heads per iteration; denom + cached exp weights
    int h1 = lane & 7;
    int es = lane >> 3;
    float a2h = a2[node * N_HEADS + h1];

    float l = 0.f;
    for (int base = 0; base < deg; base += 8) {
        int e = base + es;
        if (e < deg) {
            int s = esrc[off + e];
            float t = a1[s * N_HEADS + h1] + a2h;
            t = t > 0.f ? t : 0.2f * t;
            float ww = __expf(t);
            l += ww;
            if (e < DEG_CAP) {
                w[e * N_HEADS + h1] = ww;
                if (h1 == 0) si[e] = s;
            }
        }
    }
    l += __shfl_xor(l, 8);
    l += __shfl_xor(l, 16);
    l += __shfl_xor(l, 32);
    float invl = (deg > 0) ? 1.f / l : 0.f;

    int lim = min(deg, DEG_CAP);
    for (int e = es; e < lim; e += 8) w[e * N_HEADS + h1] *= invl;

    // phase B: one edge per iter, whole wave reads one 256 B ft row coalesced
    int hl = lane >> 3;
    float invl2 = __shfl(invl, hl);
    float a2h2  = __shfl(a2h, hl);

    float accx = 0.f, accy = 0.f;
#pragma unroll 16
    for (int j = 0; j < lim; j++) {
        float ww = w[j * N_HEADS + hl];
        int s = si[j];
        unsigned int p = *(const unsigned int*)(ftb + (size_t)s * HD + lane * 2);
        float fx = __uint_as_float(p << 16);
        float fy = __uint_as_float(p & 0xffff0000u);
        accx = fmaf(ww, fx, accx);
        accy = fmaf(ww, fy, accy);
    }
    for (int j = DEG_CAP; j < deg; j++) {   // statistically never; correctness only
        int s = esrc[off + j];
        float t = a1[s * N_HEADS + hl] + a2h2;
        t = t > 0.f ? t : 0.2f * t;
        float ww = __expf(t) * invl2;
        unsigned int p = *(const unsigned int*)(ftb + (size_t)s * HD + lane * 2);
        accx = fmaf(ww, __uint_as_float(p << 16), accx);
        accy = fmaf(ww, __uint_as_float(p & 0xffff0000u), accy);
    }

    float2 o; o.x = accx; o.y = accy;
    *(float2*)(out + (size_t)node * HD + lane * 2) = o;
}

// ---------------- host launcher ----------------
extern "C" void kernel_launch(void* const* d_in, const int* in_sizes, int n_in,
                              void* d_out, int out_size, void* d_ws, size_t ws_size,
                              hipStream_t stream) {
    const float* x      = (const float*)d_in[0];
    const float* W      = (const float*)d_in[1];
    const float* attn_l = (const float*)d_in[2];
    const float* attn_r = (const float*)d_in[3];
    const int*   src    = (const int*)d_in[4];
    const int*   dst    = (const int*)d_in[5];
    float* out = (float*)d_out;

    char* ws = (char*)d_ws;
    size_t o = 0;
    auto alloc = [&](size_t bytes) -> char* {
        char* p = ws + o;
        o = (o + bytes + 255) & ~(size_t)255;
        return p;
    };
    unsigned short* ftb  = (unsigned short*)alloc((size_t)N_NODES * HD * 2);   // 12.8 MB
    float* a1            = (float*)alloc((size_t)N_NODES * N_HEADS * 4);
    float* a2            = (float*)alloc((size_t)N_NODES * N_HEADS * 4);
    unsigned short* Wb   = (unsigned short*)alloc((size_t)HD * IN_DIM * 2);    // 32 KB
    unsigned int* region = (unsigned int*)alloc((size_t)NBUCK * BCAP * 4);     // 8.0 MB
    int* bucket_cnt      = (int*)alloc((size_t)NBUCK * 4);
    int* ovf_cnt         = (int*)alloc(4);
    unsigned int* ovf    = (unsigned int*)alloc((size_t)N_EDGES * 4);          // 6.4 MB
    int* offs            = (int*)alloc((size_t)(N_NODES + 1) * 4);
    unsigned short* esrc = (unsigned short*)alloc((size_t)N_EDGES * 2);        // 3.2 MB

    (void)in_sizes; (void)n_in; (void)out_size; (void)ws_size;

    k_prep<<<16, 256, 0, stream>>>(W, Wb, bucket_cnt, ovf_cnt);
    k_proj_bin<<<PBLK + BIN_BLOCKS, 256, 0, stream>>>(
        x, Wb, attn_l, attn_r, ftb, a1, a2,
        src, dst, region, bucket_cnt, ovf_cnt, ovf);
    k_place<<<NBUCK, 256, 0, stream>>>(region, bucket_cnt, ovf_cnt, ovf, offs, esrc);
    k_aggregate<<<N_NODES / 4, 256, 0, stream>>>(ftb, a1, a2, offs, esrc, out);
}